// Round 9
// baseline (497.050 us; speedup 1.0000x reference)
//
#include <hip/hip_runtime.h>
#include <hip/hip_bf16.h>
#include <stdint.h>

#define D_MODEL 1024
#define HIDDEN  2048
#define N_EXP   8
#define T_TOK   8192
#define MAXPOS  17408   // 16384 assignments + 8*128 padding
#define ROWTILES (MAXPOS/128)

typedef __attribute__((ext_vector_type(4))) float f32x4;
typedef __attribute__((ext_vector_type(8))) short short8v;

__device__ __forceinline__ unsigned short f2bf(float f) {
    union { float f; unsigned int u; } v; v.f = f;
    unsigned int u = v.u;
    unsigned int r = (u + 0x7fffu + ((u >> 16) & 1u)) >> 16;  // RNE
    return (unsigned short)r;
}

__device__ __forceinline__ void gload_lds16(const void* g, void* l) {
    __builtin_amdgcn_global_load_lds(
        reinterpret_cast<const __attribute__((address_space(1))) unsigned int*>(
            reinterpret_cast<uintptr_t>(g)),
        reinterpret_cast<__attribute__((address_space(3))) unsigned int*>(
            (uint32_t)reinterpret_cast<uintptr_t>(l)),
        16, 0, 0);
}

// ------- fused RMSNorm + gate (wave/token, no atomics) + out=x init -------
__global__ void rms_gate_kernel(const float* __restrict__ x,
                                const float* __restrict__ nw,
                                const float* __restrict__ gw,
                                unsigned short* __restrict__ tb,
                                int* __restrict__ tok_e,
                                float* __restrict__ tok_w,
                                float* __restrict__ out) {
    const int wave = threadIdx.x >> 6;
    const int lane = threadIdx.x & 63;
    const int t = blockIdx.x * 4 + wave;

    const float4* xr = (const float4*)(x + (size_t)t * D_MODEL);
    const float4* wr = (const float4*)nw;
    float4* orow = (float4*)(out + (size_t)t * D_MODEL);
    float4 xv[4], wv[4];
    #pragma unroll
    for (int j = 0; j < 4; j++) {
        xv[j] = xr[j * 64 + lane];
        wv[j] = wr[j * 64 + lane];
    }
    #pragma unroll
    for (int j = 0; j < 4; j++) orow[j * 64 + lane] = xv[j];   // out = x (residual)

    float ssq = 0.0f;
    #pragma unroll
    for (int j = 0; j < 4; j++)
        ssq += xv[j].x * xv[j].x + xv[j].y * xv[j].y + xv[j].z * xv[j].z + xv[j].w * xv[j].w;
    #pragma unroll
    for (int off = 32; off; off >>= 1) ssq += __shfl_xor(ssq, off);
    const float scale = rsqrtf(ssq * (1.0f / D_MODEL) + 1e-6f);

    float4 tn[4];
    #pragma unroll
    for (int j = 0; j < 4; j++) {
        tn[j].x = xv[j].x * wv[j].x * scale;
        tn[j].y = xv[j].y * wv[j].y * scale;
        tn[j].z = xv[j].z * wv[j].z * scale;
        tn[j].w = xv[j].w * wv[j].w * scale;
    }

    ushort4* tw = (ushort4*)(tb + (size_t)t * D_MODEL);
    #pragma unroll
    for (int j = 0; j < 4; j++) {
        ushort4 o;
        o.x = f2bf(tn[j].x); o.y = f2bf(tn[j].y);
        o.z = f2bf(tn[j].z); o.w = f2bf(tn[j].w);
        tw[j * 64 + lane] = o;
    }

    float d[8];
    #pragma unroll
    for (int e = 0; e < 8; e++) {
        d[e] = 0.0f;
        #pragma unroll
        for (int j = 0; j < 4; j++) {
            float4 g = ((const float4*)(gw + e * D_MODEL))[j * 64 + lane];
            d[e] += tn[j].x * g.x + tn[j].y * g.y + tn[j].z * g.z + tn[j].w * g.w;
        }
    }
    #pragma unroll
    for (int e = 0; e < 8; e++) {
        #pragma unroll
        for (int off = 32; off; off >>= 1) d[e] += __shfl_xor(d[e], off);
    }

    if (lane == 0) {
        int i0 = 0;
        #pragma unroll
        for (int e = 1; e < 8; e++) if (d[e] > d[i0]) i0 = e;   // ties -> lowest idx
        int i1 = -1;
        #pragma unroll
        for (int e = 0; e < 8; e++)
            if (e != i0 && (i1 < 0 || d[e] > d[i1])) i1 = e;
        float e1 = expf(d[i1] - d[i0]);
        float w0 = 1.0f / (1.0f + e1);
        ((int2*)tok_e)[t]   = make_int2(i0, i1);
        ((float2*)tok_w)[t] = make_float2(w0, e1 * w0);
    }
}

// ---------------- histogram: LDS-local, 8 global atomics per block ----------------
__global__ void hist_kernel(const int* __restrict__ tok_e, int* __restrict__ counts) {
    __shared__ int lh[8];
    if (threadIdx.x < 8) lh[threadIdx.x] = 0;
    __syncthreads();
    int i = blockIdx.x * 512 + threadIdx.x;
    atomicAdd(&lh[tok_e[i]], 1);
    atomicAdd(&lh[tok_e[i + 256]], 1);
    __syncthreads();
    if (threadIdx.x < 8) atomicAdd(&counts[threadIdx.x], lh[threadIdx.x]);
}

// ---------------- padded-offset scan + perm zero-fill ----------------
__global__ void scan_fill_kernel(int* __restrict__ perm_tok, float* __restrict__ perm_w,
                                 const int* __restrict__ counts,
                                 int* __restrict__ poff, int* __restrict__ pos_ctr) {
    int i = blockIdx.x * 256 + threadIdx.x;
    if (i < MAXPOS) { perm_tok[i] = 0; perm_w[i] = 0.0f; }
    if (blockIdx.x == 0 && threadIdx.x == 0) {
        int acc = 0; poff[0] = 0;
        #pragma unroll
        for (int e = 0; e < 8; e++) {
            pos_ctr[e] = 0;
            acc += (counts[e] + 127) & ~127;
            poff[e + 1] = acc;
        }
    }
}

// ---------------- scatter: block-level LDS reservation ----------------
__global__ void scatter_kernel(const int* __restrict__ tok_e, const float* __restrict__ tok_w,
                               const int* __restrict__ poff, int* __restrict__ pos_ctr,
                               int* __restrict__ perm_tok, float* __restrict__ perm_w) {
    __shared__ int lh[8], lbase[8];
    if (threadIdx.x < 8) lh[threadIdx.x] = 0;
    __syncthreads();
    int t = blockIdx.x * 256 + threadIdx.x;
    int2   ee = ((const int2*)tok_e)[t];
    float2 ww = ((const float2*)tok_w)[t];
    int p0 = atomicAdd(&lh[ee.x], 1);
    int p1 = atomicAdd(&lh[ee.y], 1);
    __syncthreads();
    if (threadIdx.x < 8) lbase[threadIdx.x] = atomicAdd(&pos_ctr[threadIdx.x], lh[threadIdx.x]);
    __syncthreads();
    int q0 = poff[ee.x] + lbase[ee.x] + p0;
    int q1 = poff[ee.y] + lbase[ee.y] + p1;
    perm_tok[q0] = t; perm_w[q0] = ww.x;
    perm_tok[q1] = t; perm_w[q1] = ww.y;
}

// ---------------- fp32 -> bf16 convert (both weight tensors, one launch) ----------------
__global__ void cvt2_bf16_kernel(const float4* __restrict__ a, ushort4* __restrict__ ao,
                                 const float4* __restrict__ b, ushort4* __restrict__ bo,
                                 int n4) {
    int i = blockIdx.x * 256 + threadIdx.x;
    const float4* src = (i < n4) ? a : b;
    ushort4* dst = (i < n4) ? ao : bo;
    int idx = (i < n4) ? i : i - n4;
    float4 v = src[idx];
    ushort4 o; o.x = f2bf(v.x); o.y = f2bf(v.y); o.z = f2bf(v.z); o.w = f2bf(v.w);
    dst[idx] = o;
}

// ---------------- grouped GEMM (m97 structure: 128x128 tile, BK=64) ----------------
// MODE 1: Hout = gelu(A_gathered @ W^T + b) -> bf16 (coalesced via half-tile LDS bounce)
// MODE 2: out[tok] += w * (A @ W^T + b)  via fp32 atomicAdd
template <int MODE, int K, int N>
__global__ __launch_bounds__(256) void moe_gemm_kernel(
                                const unsigned short* __restrict__ A,
                                const unsigned short* __restrict__ W,
                                const float* __restrict__ bias,
                                const int* __restrict__ perm_tok,
                                const float* __restrict__ perm_w,
                                const int* __restrict__ poff,
                                unsigned short* __restrict__ Hout,
                                float* __restrict__ Out) {
    constexpr int NT = N / 128;
    __shared__ short lds[2 * 128 * 64];          // 32 KiB: staging; reused for epilogue bounce
    short* Asm = lds;
    short* Bsm = lds + 128 * 64;

    // T1: XCD-aware swizzle (grid % 8 == 0 for both instantiations)
    const int nwg = gridDim.x;
    const int cpx = nwg >> 3;
    const int bid = (int)blockIdx.x;
    const int swz = (bid & 7) * cpx + (bid >> 3);

    const int rt = swz / NT, nt = swz % NT;
    const int row_base = rt * 128;
    if (row_base >= poff[8]) return;
    int e = 0;
    while (poff[e + 1] <= row_base) ++e;
    const int n0 = nt * 128;

    const int tid = threadIdx.x;
    const int wave = tid >> 6, lane = tid & 63;
    const int colb = (tid & 7) * 16;
    const int wr = wave >> 1, wc = wave & 1;

    size_t aoff[4], boff[4];
    #pragma unroll
    for (int i = 0; i < 4; i++) {
        int r = row_base + i * 32 + (tid >> 3);
        int arow = (MODE == 1) ? perm_tok[r] : r;
        aoff[i] = (size_t)arow * (K * 2);
        int brow = n0 + i * 32 + (tid >> 3);
        boff[i] = ((size_t)e * N + brow) * (size_t)(K * 2);
    }
    const char* Ab = (const char*)A;
    const char* Wb = (const char*)W;

    f32x4 acc[4][4];
    #pragma unroll
    for (int mi = 0; mi < 4; mi++)
        #pragma unroll
        for (int ni = 0; ni < 4; ni++) acc[mi][ni] = (f32x4)(0.0f);

    for (int k0b = 0; k0b < K * 2; k0b += 128) {
        #pragma unroll
        for (int i = 0; i < 4; i++) {
            gload_lds16(Ab + aoff[i] + k0b + colb, (char*)Asm + i * 4096 + wave * 1024);
            gload_lds16(Wb + boff[i] + k0b + colb, (char*)Bsm + i * 4096 + wave * 1024);
        }
        __syncthreads();
        #pragma unroll
        for (int kk = 0; kk < 2; kk++) {
            short8v af[4], bf[4];
            #pragma unroll
            for (int mi = 0; mi < 4; mi++)
                af[mi] = *(const short8v*)&Asm[(wr * 64 + mi * 16 + (lane & 15)) * 64 + kk * 32 + (lane >> 4) * 8];
            #pragma unroll
            for (int ni = 0; ni < 4; ni++)
                bf[ni] = *(const short8v*)&Bsm[(wc * 64 + ni * 16 + (lane & 15)) * 64 + kk * 32 + (lane >> 4) * 8];
            #pragma unroll
            for (int mi = 0; mi < 4; mi++)
                #pragma unroll
                for (int ni = 0; ni < 4; ni++)
                    acc[mi][ni] = __builtin_amdgcn_mfma_f32_16x16x32_bf16(af[mi], bf[ni], acc[mi][ni], 0, 0, 0);
        }
        __syncthreads();
    }

    if (MODE == 1) {
        // two row-half passes through a [64][136] LDS bounce (fits the 32 KiB buffer,
        // keeps 5 blocks/CU), then fully-coalesced 16B stores
        #pragma unroll
        for (int hh = 0; hh < 2; hh++) {
            if (wr == hh) {
                #pragma unroll
                for (int mi = 0; mi < 4; mi++) {
                    #pragma unroll
                    for (int ni = 0; ni < 4; ni++) {
                        int lc = wc * 64 + ni * 16 + (lane & 15);
                        float bv = bias[e * N + n0 + lc];
                        #pragma unroll
                        for (int j = 0; j < 4; j++) {
                            int lr = mi * 16 + (lane >> 4) * 4 + j;     // [0,64)
                            float v = acc[mi][ni][j] + bv;
                            v = 0.5f * v * (1.0f + erff(v * 0.70710678118654752f));
                            lds[lr * 136 + lc] = (short)f2bf(v);
                        }
                    }
                }
            }
            __syncthreads();
            {
                const int rr = tid >> 4;        // [0,16)
                const int cc = tid & 15;        // 16B chunks in 128-col row
                #pragma unroll
                for (int p = 0; p < 4; p++) {
                    int lr = p * 16 + rr;       // [0,64)
                    short8v v = *(const short8v*)&lds[lr * 136 + cc * 8];
                    *(short8v*)(Hout + (size_t)(row_base + hh * 64 + lr) * N + n0 + cc * 8) = v;
                }
            }
            __syncthreads();
        }
    } else {
        #pragma unroll
        for (int mi = 0; mi < 4; mi++) {
            #pragma unroll
            for (int j = 0; j < 4; j++) {
                int r = row_base + wr * 64 + mi * 16 + (lane >> 4) * 4 + j;
                float wgt = perm_w[r];
                if (wgt != 0.0f) {
                    int tok = perm_tok[r];
                    float* orow = Out + (size_t)tok * N;
                    #pragma unroll
                    for (int ni = 0; ni < 4; ni++) {
                        int c = n0 + wc * 64 + ni * 16 + (lane & 15);
                        atomicAdd(&orow[c], wgt * (acc[mi][ni][j] + bias[e * N + c]));
                    }
                }
            }
        }
    }
}

// ---------------- launch ----------------
extern "C" void kernel_launch(void* const* d_in, const int* in_sizes, int n_in,
                              void* d_out, int out_size, void* d_ws, size_t ws_size,
                              hipStream_t stream) {
    const float* x  = (const float*)d_in[0];
    const float* nw = (const float*)d_in[1];
    const float* gw = (const float*)d_in[2];
    const float* w1 = (const float*)d_in[3];
    const float* b1 = (const float*)d_in[4];
    const float* w2 = (const float*)d_in[5];
    const float* b2 = (const float*)d_in[6];
    float* out = (float*)d_out;
    char* ws = (char*)d_ws;

    size_t off = 0;
    unsigned short* tb  = (unsigned short*)(ws + off); off += (size_t)T_TOK * D_MODEL * 2;
    unsigned short* w1b = (unsigned short*)(ws + off); off += (size_t)N_EXP * HIDDEN * D_MODEL * 2;
    unsigned short* w2b = (unsigned short*)(ws + off); off += (size_t)N_EXP * D_MODEL * HIDDEN * 2;
    unsigned short* h   = (unsigned short*)(ws + off); off += (size_t)MAXPOS * HIDDEN * 2;
    int*   perm_tok = (int*)(ws + off);   off += MAXPOS * 4;
    float* perm_w   = (float*)(ws + off); off += MAXPOS * 4;
    int*   tok_e    = (int*)(ws + off);   off += T_TOK * 2 * 4;
    float* tok_w    = (float*)(ws + off); off += T_TOK * 2 * 4;
    int*   meta     = (int*)(ws + off);   // counts[8] | pos_ctr[8] | poff[9]
    int* counts  = meta;
    int* pos_ctr = meta + 8;
    int* poff    = meta + 16;

    hipMemsetAsync(meta, 0, 32, stream);   // zero counts

    rms_gate_kernel<<<T_TOK / 4, 256, 0, stream>>>(x, nw, gw, tb, tok_e, tok_w, out);

    const int n4 = N_EXP * HIDDEN * D_MODEL / 4;
    cvt2_bf16_kernel<<<2 * n4 / 256, 256, 0, stream>>>(
        (const float4*)w1, (ushort4*)w1b, (const float4*)w2, (ushort4*)w2b, n4);

    hist_kernel<<<32, 256, 0, stream>>>(tok_e, counts);
    scan_fill_kernel<<<MAXPOS / 256, 256, 0, stream>>>(perm_tok, perm_w, counts, poff, pos_ctr);
    scatter_kernel<<<T_TOK / 256, 256, 0, stream>>>(tok_e, tok_w, poff, pos_ctr, perm_tok, perm_w);

    moe_gemm_kernel<1, D_MODEL, HIDDEN><<<ROWTILES * (HIDDEN / 128), 256, 0, stream>>>(
        tb, w1b, b1, perm_tok, perm_w, poff, h, nullptr);
    moe_gemm_kernel<2, HIDDEN, D_MODEL><<<ROWTILES * (D_MODEL / 128), 256, 0, stream>>>(
        h, w2b, b2, perm_tok, perm_w, poff, nullptr, out);
}

// Round 10
// 457.055 us; speedup vs baseline: 1.0875x; 1.0875x over previous
//
#include <hip/hip_runtime.h>
#include <hip/hip_bf16.h>
#include <stdint.h>

#define D_MODEL 1024
#define HIDDEN  2048
#define N_EXP   8
#define T_TOK   8192
#define MAXPOS  17408   // 16384 assignments + 8*128 padding
#define ROWTILES (MAXPOS/128)

typedef __attribute__((ext_vector_type(4))) float f32x4;
typedef __attribute__((ext_vector_type(8))) short short8v;

__device__ __forceinline__ unsigned short f2bf(float f) {
    union { float f; unsigned int u; } v; v.f = f;
    unsigned int u = v.u;
    unsigned int r = (u + 0x7fffu + ((u >> 16) & 1u)) >> 16;  // RNE
    return (unsigned short)r;
}

__device__ __forceinline__ void gload_lds16(const void* g, void* l) {
    __builtin_amdgcn_global_load_lds(
        reinterpret_cast<const __attribute__((address_space(1))) unsigned int*>(
            reinterpret_cast<uintptr_t>(g)),
        reinterpret_cast<__attribute__((address_space(3))) unsigned int*>(
            (uint32_t)reinterpret_cast<uintptr_t>(l)),
        16, 0, 0);
}

// ------- fused RMSNorm + gate (wave/token, no atomics) + out=x init -------
__global__ void rms_gate_kernel(const float* __restrict__ x,
                                const float* __restrict__ nw,
                                const float* __restrict__ gw,
                                unsigned short* __restrict__ tb,
                                int* __restrict__ tok_e,
                                float* __restrict__ tok_w,
                                float* __restrict__ out) {
    const int wave = threadIdx.x >> 6;
    const int lane = threadIdx.x & 63;
    const int t = blockIdx.x * 4 + wave;

    const float4* xr = (const float4*)(x + (size_t)t * D_MODEL);
    const float4* wr = (const float4*)nw;
    float4* orow = (float4*)(out + (size_t)t * D_MODEL);
    float4 xv[4], wv[4];
    #pragma unroll
    for (int j = 0; j < 4; j++) {
        xv[j] = xr[j * 64 + lane];
        wv[j] = wr[j * 64 + lane];
    }
    #pragma unroll
    for (int j = 0; j < 4; j++) orow[j * 64 + lane] = xv[j];   // out = x (residual)

    float ssq = 0.0f;
    #pragma unroll
    for (int j = 0; j < 4; j++)
        ssq += xv[j].x * xv[j].x + xv[j].y * xv[j].y + xv[j].z * xv[j].z + xv[j].w * xv[j].w;
    #pragma unroll
    for (int off = 32; off; off >>= 1) ssq += __shfl_xor(ssq, off);
    const float scale = rsqrtf(ssq * (1.0f / D_MODEL) + 1e-6f);

    float4 tn[4];
    #pragma unroll
    for (int j = 0; j < 4; j++) {
        tn[j].x = xv[j].x * wv[j].x * scale;
        tn[j].y = xv[j].y * wv[j].y * scale;
        tn[j].z = xv[j].z * wv[j].z * scale;
        tn[j].w = xv[j].w * wv[j].w * scale;
    }

    ushort4* tw = (ushort4*)(tb + (size_t)t * D_MODEL);
    #pragma unroll
    for (int j = 0; j < 4; j++) {
        ushort4 o;
        o.x = f2bf(tn[j].x); o.y = f2bf(tn[j].y);
        o.z = f2bf(tn[j].z); o.w = f2bf(tn[j].w);
        tw[j * 64 + lane] = o;
    }

    float d[8];
    #pragma unroll
    for (int e = 0; e < 8; e++) {
        d[e] = 0.0f;
        #pragma unroll
        for (int j = 0; j < 4; j++) {
            float4 g = ((const float4*)(gw + e * D_MODEL))[j * 64 + lane];
            d[e] += tn[j].x * g.x + tn[j].y * g.y + tn[j].z * g.z + tn[j].w * g.w;
        }
    }
    #pragma unroll
    for (int e = 0; e < 8; e++) {
        #pragma unroll
        for (int off = 32; off; off >>= 1) d[e] += __shfl_xor(d[e], off);
    }

    if (lane == 0) {
        int i0 = 0;
        #pragma unroll
        for (int e = 1; e < 8; e++) if (d[e] > d[i0]) i0 = e;   // ties -> lowest idx
        int i1 = -1;
        #pragma unroll
        for (int e = 0; e < 8; e++)
            if (e != i0 && (i1 < 0 || d[e] > d[i1])) i1 = e;
        float e1 = expf(d[i1] - d[i0]);
        float w0 = 1.0f / (1.0f + e1);
        ((int2*)tok_e)[t]   = make_int2(i0, i1);
        ((float2*)tok_w)[t] = make_float2(w0, e1 * w0);
    }
}

// ---------------- histogram: LDS-local, 8 global atomics per block ----------------
__global__ void hist_kernel(const int* __restrict__ tok_e, int* __restrict__ counts) {
    __shared__ int lh[8];
    if (threadIdx.x < 8) lh[threadIdx.x] = 0;
    __syncthreads();
    int i = blockIdx.x * 512 + threadIdx.x;
    atomicAdd(&lh[tok_e[i]], 1);
    atomicAdd(&lh[tok_e[i + 256]], 1);
    __syncthreads();
    if (threadIdx.x < 8) atomicAdd(&counts[threadIdx.x], lh[threadIdx.x]);
}

// ---------------- padded-offset scan + perm zero-fill ----------------
__global__ void scan_fill_kernel(int* __restrict__ perm_tok, float* __restrict__ perm_w,
                                 const int* __restrict__ counts,
                                 int* __restrict__ poff, int* __restrict__ pos_ctr) {
    int i = blockIdx.x * 256 + threadIdx.x;
    if (i < MAXPOS) { perm_tok[i] = 0; perm_w[i] = 0.0f; }
    if (blockIdx.x == 0 && threadIdx.x == 0) {
        int acc = 0; poff[0] = 0;
        #pragma unroll
        for (int e = 0; e < 8; e++) {
            pos_ctr[e] = 0;
            acc += (counts[e] + 127) & ~127;
            poff[e + 1] = acc;
        }
    }
}

// ---------------- scatter: block-level LDS reservation ----------------
__global__ void scatter_kernel(const int* __restrict__ tok_e, const float* __restrict__ tok_w,
                               const int* __restrict__ poff, int* __restrict__ pos_ctr,
                               int* __restrict__ perm_tok, float* __restrict__ perm_w) {
    __shared__ int lh[8], lbase[8];
    if (threadIdx.x < 8) lh[threadIdx.x] = 0;
    __syncthreads();
    int t = blockIdx.x * 256 + threadIdx.x;
    int2   ee = ((const int2*)tok_e)[t];
    float2 ww = ((const float2*)tok_w)[t];
    int p0 = atomicAdd(&lh[ee.x], 1);
    int p1 = atomicAdd(&lh[ee.y], 1);
    __syncthreads();
    if (threadIdx.x < 8) lbase[threadIdx.x] = atomicAdd(&pos_ctr[threadIdx.x], lh[threadIdx.x]);
    __syncthreads();
    int q0 = poff[ee.x] + lbase[ee.x] + p0;
    int q1 = poff[ee.y] + lbase[ee.y] + p1;
    perm_tok[q0] = t; perm_w[q0] = ww.x;
    perm_tok[q1] = t; perm_w[q1] = ww.y;
}

// ---------------- fp32 -> bf16 convert (both weight tensors, one launch) ----------------
__global__ void cvt2_bf16_kernel(const float4* __restrict__ a, ushort4* __restrict__ ao,
                                 const float4* __restrict__ b, ushort4* __restrict__ bo,
                                 int n4) {
    int i = blockIdx.x * 256 + threadIdx.x;
    const float4* src = (i < n4) ? a : b;
    ushort4* dst = (i < n4) ? ao : bo;
    int idx = (i < n4) ? i : i - n4;
    float4 v = src[idx];
    ushort4 o; o.x = f2bf(v.x); o.y = f2bf(v.y); o.z = f2bf(v.z); o.w = f2bf(v.w);
    dst[idx] = o;
}

// ---------------- grouped GEMM (m97 structure: 128x128 tile, BK=64) ----------------
// MODE 1: Hout = gelu(A_gathered @ W^T + b) -> bf16, single-pass [128][136] LDS
//         bounce + coalesced 16B stores (R3-measured fastest epilogue: 175us)
// MODE 2: out[tok] += w * (A @ W^T + b)  via fp32 atomicAdd (R2-measured; beats
//         obuf+combine by ~45us)
template <int MODE, int K, int N>
__global__ __launch_bounds__(256) void moe_gemm_kernel(
                                const unsigned short* __restrict__ A,
                                const unsigned short* __restrict__ W,
                                const float* __restrict__ bias,
                                const int* __restrict__ perm_tok,
                                const float* __restrict__ perm_w,
                                const int* __restrict__ poff,
                                unsigned short* __restrict__ Hout,
                                float* __restrict__ Out) {
    constexpr int NT = N / 128;
    // MODE1 needs 17408 shorts for the [128][136] epilogue bounce; MODE2 only staging.
    __shared__ short lds[MODE == 1 ? 17408 : 16384];
    short* Asm = lds;
    short* Bsm = lds + 128 * 64;

    // T1: XCD-aware swizzle (grid % 8 == 0 for both instantiations)
    const int nwg = gridDim.x;
    const int cpx = nwg >> 3;
    const int bid = (int)blockIdx.x;
    const int swz = (bid & 7) * cpx + (bid >> 3);

    const int rt = swz / NT, nt = swz % NT;
    const int row_base = rt * 128;
    if (row_base >= poff[8]) return;
    int e = 0;
    while (poff[e + 1] <= row_base) ++e;
    const int n0 = nt * 128;

    const int tid = threadIdx.x;
    const int wave = tid >> 6, lane = tid & 63;
    const int colb = (tid & 7) * 16;
    const int wr = wave >> 1, wc = wave & 1;

    size_t aoff[4], boff[4];
    #pragma unroll
    for (int i = 0; i < 4; i++) {
        int r = row_base + i * 32 + (tid >> 3);
        int arow = (MODE == 1) ? perm_tok[r] : r;
        aoff[i] = (size_t)arow * (K * 2);
        int brow = n0 + i * 32 + (tid >> 3);
        boff[i] = ((size_t)e * N + brow) * (size_t)(K * 2);
    }
    const char* Ab = (const char*)A;
    const char* Wb = (const char*)W;

    f32x4 acc[4][4];
    #pragma unroll
    for (int mi = 0; mi < 4; mi++)
        #pragma unroll
        for (int ni = 0; ni < 4; ni++) acc[mi][ni] = (f32x4)(0.0f);

    for (int k0b = 0; k0b < K * 2; k0b += 128) {
        #pragma unroll
        for (int i = 0; i < 4; i++) {
            gload_lds16(Ab + aoff[i] + k0b + colb, (char*)Asm + i * 4096 + wave * 1024);
            gload_lds16(Wb + boff[i] + k0b + colb, (char*)Bsm + i * 4096 + wave * 1024);
        }
        __syncthreads();
        #pragma unroll
        for (int kk = 0; kk < 2; kk++) {
            short8v af[4], bf[4];
            #pragma unroll
            for (int mi = 0; mi < 4; mi++)
                af[mi] = *(const short8v*)&Asm[(wr * 64 + mi * 16 + (lane & 15)) * 64 + kk * 32 + (lane >> 4) * 8];
            #pragma unroll
            for (int ni = 0; ni < 4; ni++)
                bf[ni] = *(const short8v*)&Bsm[(wc * 64 + ni * 16 + (lane & 15)) * 64 + kk * 32 + (lane >> 4) * 8];
            #pragma unroll
            for (int mi = 0; mi < 4; mi++)
                #pragma unroll
                for (int ni = 0; ni < 4; ni++)
                    acc[mi][ni] = __builtin_amdgcn_mfma_f32_16x16x32_bf16(af[mi], bf[ni], acc[mi][ni], 0, 0, 0);
        }
        __syncthreads();
    }

    if (MODE == 1) {
        // single-pass bounce: all waves write their quadrant into [128][136], then
        // 256 threads store 128x128 bf16 fully coalesced (16B per lane)
        #pragma unroll
        for (int mi = 0; mi < 4; mi++) {
            #pragma unroll
            for (int ni = 0; ni < 4; ni++) {
                int lc = wc * 64 + ni * 16 + (lane & 15);
                float bv = bias[e * N + n0 + lc];
                #pragma unroll
                for (int j = 0; j < 4; j++) {
                    int lr = wr * 64 + mi * 16 + (lane >> 4) * 4 + j;
                    float v = acc[mi][ni][j] + bv;
                    v = 0.5f * v * (1.0f + erff(v * 0.70710678118654752f));  // exact gelu
                    lds[lr * 136 + lc] = (short)f2bf(v);
                }
            }
        }
        __syncthreads();
        {
            const int rr = tid >> 4;        // [0,16)
            const int cc = tid & 15;        // 16B chunks within 256B row
            #pragma unroll
            for (int p = 0; p < 8; p++) {
                int lr = p * 16 + rr;
                short8v vv = *(const short8v*)&lds[lr * 136 + cc * 8];
                *(short8v*)(Hout + (size_t)(row_base + lr) * N + n0 + cc * 8) = vv;
            }
        }
    } else {
        #pragma unroll
        for (int mi = 0; mi < 4; mi++) {
            #pragma unroll
            for (int j = 0; j < 4; j++) {
                int r = row_base + wr * 64 + mi * 16 + (lane >> 4) * 4 + j;
                float wgt = perm_w[r];
                if (wgt != 0.0f) {
                    int tok = perm_tok[r];
                    float* orow = Out + (size_t)tok * N;
                    #pragma unroll
                    for (int ni = 0; ni < 4; ni++) {
                        int c = n0 + wc * 64 + ni * 16 + (lane & 15);
                        atomicAdd(&orow[c], wgt * (acc[mi][ni][j] + bias[e * N + c]));
                    }
                }
            }
        }
    }
}

// ---------------- launch ----------------
extern "C" void kernel_launch(void* const* d_in, const int* in_sizes, int n_in,
                              void* d_out, int out_size, void* d_ws, size_t ws_size,
                              hipStream_t stream) {
    const float* x  = (const float*)d_in[0];
    const float* nw = (const float*)d_in[1];
    const float* gw = (const float*)d_in[2];
    const float* w1 = (const float*)d_in[3];
    const float* b1 = (const float*)d_in[4];
    const float* w2 = (const float*)d_in[5];
    const float* b2 = (const float*)d_in[6];
    float* out = (float*)d_out;
    char* ws = (char*)d_ws;

    size_t off = 0;
    unsigned short* tb  = (unsigned short*)(ws + off); off += (size_t)T_TOK * D_MODEL * 2;
    unsigned short* w1b = (unsigned short*)(ws + off); off += (size_t)N_EXP * HIDDEN * D_MODEL * 2;
    unsigned short* w2b = (unsigned short*)(ws + off); off += (size_t)N_EXP * D_MODEL * HIDDEN * 2;
    unsigned short* h   = (unsigned short*)(ws + off); off += (size_t)MAXPOS * HIDDEN * 2;
    int*   perm_tok = (int*)(ws + off);   off += MAXPOS * 4;
    float* perm_w   = (float*)(ws + off); off += MAXPOS * 4;
    int*   tok_e    = (int*)(ws + off);   off += T_TOK * 2 * 4;
    float* tok_w    = (float*)(ws + off); off += T_TOK * 2 * 4;
    int*   meta     = (int*)(ws + off);   // counts[8] | pos_ctr[8] | poff[9]
    int* counts  = meta;
    int* pos_ctr = meta + 8;
    int* poff    = meta + 16;

    hipMemsetAsync(meta, 0, 32, stream);   // zero counts

    rms_gate_kernel<<<T_TOK / 4, 256, 0, stream>>>(x, nw, gw, tb, tok_e, tok_w, out);

    const int n4 = N_EXP * HIDDEN * D_MODEL / 4;
    cvt2_bf16_kernel<<<2 * n4 / 256, 256, 0, stream>>>(
        (const float4*)w1, (ushort4*)w1b, (const float4*)w2, (ushort4*)w2b, n4);

    hist_kernel<<<32, 256, 0, stream>>>(tok_e, counts);
    scan_fill_kernel<<<MAXPOS / 256, 256, 0, stream>>>(perm_tok, perm_w, counts, poff, pos_ctr);
    scatter_kernel<<<T_TOK / 256, 256, 0, stream>>>(tok_e, tok_w, poff, pos_ctr, perm_tok, perm_w);

    moe_gemm_kernel<1, D_MODEL, HIDDEN><<<ROWTILES * (HIDDEN / 128), 256, 0, stream>>>(
        tb, w1b, b1, perm_tok, perm_w, poff, h, nullptr);
    moe_gemm_kernel<2, HIDDEN, D_MODEL><<<ROWTILES * (D_MODEL / 128), 256, 0, stream>>>(
        h, w2b, b2, perm_tok, perm_w, poff, nullptr, out);
}